// Round 1
// baseline (1161.822 us; speedup 1.0000x reference)
//
#include <hip/hip_runtime.h>

#define Bq   8
#define Cc   512
#define Ll   4096   // H*W
#define KV2  1024   // 2C

#define BM 64
#define BN 64
#define BK 32
#define PAD 4       // pad for transposed (k-major) LDS tiles: row stride 68 floats, 16B-aligned

// Helper: row pointer into the virtual kv = concat(spatial, multi) [B, 2C, L]
__device__ __forceinline__ const float* kv_row(const float* __restrict__ sp,
                                               const float* __restrict__ ms,
                                               int b, int k) {
    return (k < Cc) ? (sp + ((size_t)b * Cc + k) * Ll)
                    : (ms + ((size_t)b * Cc + (k - Cc)) * Ll);
}

// ---------------------------------------------------------------------------
// K1: attn[b, m, n] = alpha * sum_l Q[b,m,l] * KV[b,n,l]   (NT gemm)
// M=Cc=512, N=KV2=1024, K=Ll=4096
// ---------------------------------------------------------------------------
__global__ __launch_bounds__(256) void k1_logits(const float* __restrict__ x,
                                                 const float* __restrict__ sp,
                                                 const float* __restrict__ ms,
                                                 const float* __restrict__ scale,
                                                 float* __restrict__ attn) {
    __shared__ __align__(16) float As[BK][BM + PAD];
    __shared__ __align__(16) float Bs[BK][BN + PAD];

    const int b  = blockIdx.z;
    const int m0 = blockIdx.y * BM;
    const int n0 = blockIdx.x * BN;
    const int t  = threadIdx.x;
    const int tx = t & 15, ty = t >> 4;
    const int q  = t & 7;      // k-quad (BK/4 = 8 quads)
    const int r  = t >> 3;     // row 0..31

    const float alpha = scale[0] * (1.0f / 64.0f);  // L^-0.5 = 1/64
    const float* Abase = x + (size_t)b * Cc * Ll;

    float acc[4][4] = {};

    for (int k0 = 0; k0 < Ll; k0 += BK) {
        #pragma unroll
        for (int h = 0; h < 2; ++h) {
            const int row = r + 32 * h;
            float4 v = *(const float4*)(Abase + (size_t)(m0 + row) * Ll + k0 + 4 * q);
            As[4*q+0][row] = v.x; As[4*q+1][row] = v.y;
            As[4*q+2][row] = v.z; As[4*q+3][row] = v.w;
        }
        #pragma unroll
        for (int h = 0; h < 2; ++h) {
            const int row = r + 32 * h;
            const float* Brow = kv_row(sp, ms, b, n0 + row);
            float4 v = *(const float4*)(Brow + k0 + 4 * q);
            Bs[4*q+0][row] = v.x; Bs[4*q+1][row] = v.y;
            Bs[4*q+2][row] = v.z; Bs[4*q+3][row] = v.w;
        }
        __syncthreads();
        #pragma unroll
        for (int k = 0; k < BK; ++k) {
            float a[4], bb[4];
            *(float4*)a  = *(const float4*)&As[k][4 * ty];
            *(float4*)bb = *(const float4*)&Bs[k][4 * tx];
            #pragma unroll
            for (int i = 0; i < 4; ++i)
                #pragma unroll
                for (int j = 0; j < 4; ++j)
                    acc[i][j] += a[i] * bb[j];
        }
        __syncthreads();
    }

    #pragma unroll
    for (int i = 0; i < 4; ++i) {
        const int m = m0 + 4 * ty + i;
        float4 o;
        o.x = alpha * acc[i][0]; o.y = alpha * acc[i][1];
        o.z = alpha * acc[i][2]; o.w = alpha * acc[i][3];
        *(float4*)(attn + ((size_t)b * Cc + m) * KV2 + n0 + 4 * tx) = o;
    }
}

// ---------------------------------------------------------------------------
// K2: softmax over last dim (1024) of attn [B*C rows], in place
// ---------------------------------------------------------------------------
__global__ __launch_bounds__(256) void k2_softmax(float* __restrict__ attn) {
    float* p = attn + (size_t)blockIdx.x * KV2;
    const int t = threadIdx.x;
    const int lane = t & 63, wv = t >> 6;

    float4 v = ((const float4*)p)[t];
    float m = fmaxf(fmaxf(v.x, v.y), fmaxf(v.z, v.w));
    #pragma unroll
    for (int off = 32; off; off >>= 1) m = fmaxf(m, __shfl_down(m, off));

    __shared__ float redm[4];
    if (lane == 0) redm[wv] = m;
    __syncthreads();
    m = fmaxf(fmaxf(redm[0], redm[1]), fmaxf(redm[2], redm[3]));

    v.x = __expf(v.x - m); v.y = __expf(v.y - m);
    v.z = __expf(v.z - m); v.w = __expf(v.w - m);
    float s = v.x + v.y + v.z + v.w;
    #pragma unroll
    for (int off = 32; off; off >>= 1) s += __shfl_down(s, off);

    __shared__ float reds[4];
    if (lane == 0) reds[wv] = s;
    __syncthreads();
    s = reds[0] + reds[1] + reds[2] + reds[3];

    const float inv = 1.0f / s;
    v.x *= inv; v.y *= inv; v.z *= inv; v.w *= inv;
    ((float4*)p)[t] = v;
}

// ---------------------------------------------------------------------------
// K3: attn2[b, m, n] = sum_c W[m,c] * attn[b,c,n]   (NN gemm)
// M=Cc, N=KV2, K=Cc=512
// ---------------------------------------------------------------------------
__global__ __launch_bounds__(256) void k3_wattn(const float* __restrict__ W,
                                                const float* __restrict__ attn,
                                                float* __restrict__ attn2) {
    __shared__ __align__(16) float As[BK][BM + PAD];
    __shared__ __align__(16) float Bs[BK][BN];

    const int b  = blockIdx.z;
    const int m0 = blockIdx.y * BM;
    const int n0 = blockIdx.x * BN;
    const int t  = threadIdx.x;
    const int tx = t & 15, ty = t >> 4;
    const int q  = t & 7, r = t >> 3;       // A-tile load indices
    const int c4 = t & 15, kr = t >> 4;     // B-tile load indices

    const float* Bbase = attn + (size_t)b * Cc * KV2;
    float acc[4][4] = {};

    for (int k0 = 0; k0 < Cc; k0 += BK) {
        #pragma unroll
        for (int h = 0; h < 2; ++h) {
            const int row = r + 32 * h;
            float4 v = *(const float4*)(W + (size_t)(m0 + row) * Cc + k0 + 4 * q);
            As[4*q+0][row] = v.x; As[4*q+1][row] = v.y;
            As[4*q+2][row] = v.z; As[4*q+3][row] = v.w;
        }
        #pragma unroll
        for (int h = 0; h < 2; ++h) {
            const int k = kr + 16 * h;
            float4 v = *(const float4*)(Bbase + (size_t)(k0 + k) * KV2 + n0 + 4 * c4);
            *(float4*)&Bs[k][4 * c4] = v;
        }
        __syncthreads();
        #pragma unroll
        for (int k = 0; k < BK; ++k) {
            float a[4], bb[4];
            *(float4*)a  = *(const float4*)&As[k][4 * ty];
            *(float4*)bb = *(const float4*)&Bs[k][4 * tx];
            #pragma unroll
            for (int i = 0; i < 4; ++i)
                #pragma unroll
                for (int j = 0; j < 4; ++j)
                    acc[i][j] += a[i] * bb[j];
        }
        __syncthreads();
    }

    #pragma unroll
    for (int i = 0; i < 4; ++i) {
        const int m = m0 + 4 * ty + i;
        float4 o;
        o.x = acc[i][0]; o.y = acc[i][1]; o.z = acc[i][2]; o.w = acc[i][3];
        *(float4*)(attn2 + ((size_t)b * Cc + m) * KV2 + n0 + 4 * tx) = o;
    }
}

// ---------------------------------------------------------------------------
// K4: out[b, m, l] = sum_k attn2[b,m,k] * KV[b,k,l] + bias[m]   (NN gemm)
// M=Cc, N=Ll=4096, K=KV2=1024
// ---------------------------------------------------------------------------
__global__ __launch_bounds__(256) void k4_out(const float* __restrict__ attn2,
                                              const float* __restrict__ sp,
                                              const float* __restrict__ ms,
                                              const float* __restrict__ bias,
                                              float* __restrict__ out) {
    __shared__ __align__(16) float As[BK][BM + PAD];
    __shared__ __align__(16) float Bs[BK][BN];

    const int b  = blockIdx.z;
    const int m0 = blockIdx.y * BM;
    const int n0 = blockIdx.x * BN;
    const int t  = threadIdx.x;
    const int tx = t & 15, ty = t >> 4;
    const int q  = t & 7, r = t >> 3;
    const int c4 = t & 15, kr = t >> 4;

    const float* Abase = attn2 + (size_t)b * Cc * KV2;
    float acc[4][4] = {};

    for (int k0 = 0; k0 < KV2; k0 += BK) {
        #pragma unroll
        for (int h = 0; h < 2; ++h) {
            const int row = r + 32 * h;
            float4 v = *(const float4*)(Abase + (size_t)(m0 + row) * KV2 + k0 + 4 * q);
            As[4*q+0][row] = v.x; As[4*q+1][row] = v.y;
            As[4*q+2][row] = v.z; As[4*q+3][row] = v.w;
        }
        #pragma unroll
        for (int h = 0; h < 2; ++h) {
            const int k = kr + 16 * h;
            const float* Brow = kv_row(sp, ms, b, k0 + k);
            float4 v = *(const float4*)(Brow + n0 + 4 * c4);
            *(float4*)&Bs[k][4 * c4] = v;
        }
        __syncthreads();
        #pragma unroll
        for (int k = 0; k < BK; ++k) {
            float a[4], bb[4];
            *(float4*)a  = *(const float4*)&As[k][4 * ty];
            *(float4*)bb = *(const float4*)&Bs[k][4 * tx];
            #pragma unroll
            for (int i = 0; i < 4; ++i)
                #pragma unroll
                for (int j = 0; j < 4; ++j)
                    acc[i][j] += a[i] * bb[j];
        }
        __syncthreads();
    }

    #pragma unroll
    for (int i = 0; i < 4; ++i) {
        const int m = m0 + 4 * ty + i;
        const float bm = bias[m];
        float4 o;
        o.x = acc[i][0] + bm; o.y = acc[i][1] + bm;
        o.z = acc[i][2] + bm; o.w = acc[i][3] + bm;
        *(float4*)(out + ((size_t)b * Cc + m) * Ll + n0 + 4 * tx) = o;
    }
}

// ---------------------------------------------------------------------------
extern "C" void kernel_launch(void* const* d_in, const int* in_sizes, int n_in,
                              void* d_out, int out_size, void* d_ws, size_t ws_size,
                              hipStream_t stream) {
    const float* x     = (const float*)d_in[0];
    const float* sp    = (const float*)d_in[1];
    const float* ms    = (const float*)d_in[2];
    const float* scale = (const float*)d_in[3];
    const float* W     = (const float*)d_in[4];
    const float* bias  = (const float*)d_in[5];
    float* out = (float*)d_out;

    float* attn  = (float*)d_ws;                      // [B, C, 2C] = 16.78 MB
    float* attn2 = attn + (size_t)Bq * Cc * KV2;      // [B, C, 2C] = 16.78 MB

    dim3 blk(256);
    k1_logits <<<dim3(KV2 / BN, Cc / BM, Bq), blk, 0, stream>>>(x, sp, ms, scale, attn);
    k2_softmax<<<dim3(Bq * Cc),              blk, 0, stream>>>(attn);
    k3_wattn  <<<dim3(KV2 / BN, Cc / BM, Bq), blk, 0, stream>>>(W, attn, attn2);
    k4_out    <<<dim3(Ll / BN, Cc / BM, Bq), blk, 0, stream>>>(attn2, sp, ms, bias, out);
}

// Round 2
// 475.184 us; speedup vs baseline: 2.4450x; 2.4450x over previous
//
#include <hip/hip_runtime.h>

#define Bq   8
#define Cc   512
#define Ll   4096   // H*W
#define KV2  1024   // 2C

typedef _Float16 f16;
typedef __attribute__((ext_vector_type(4))) _Float16 f16x4;
typedef __attribute__((ext_vector_type(8))) _Float16 f16x8;
typedef __attribute__((ext_vector_type(4))) float    f32x4;

// ===========================================================================
// FAST PATH (needs 244 MB workspace): fp16-split MFMA pipeline
// ===========================================================================

// --- P: elementwise fp32 -> (hi, lo) fp16 split.  n4 = n/4 --------------
__global__ __launch_bounds__(256) void p_split(const float* __restrict__ in,
                                               f16* __restrict__ hi,
                                               f16* __restrict__ lo, int n4) {
    int i = blockIdx.x * 256 + threadIdx.x;
    if (i >= n4) return;
    float4 v = ((const float4*)in)[i];
    f16 h0 = (f16)v.x, h1 = (f16)v.y, h2 = (f16)v.z, h3 = (f16)v.w;
    f16x4 hv; hv[0] = h0; hv[1] = h1; hv[2] = h2; hv[3] = h3;
    f16x4 lv;
    lv[0] = (f16)(v.x - (float)h0); lv[1] = (f16)(v.y - (float)h1);
    lv[2] = (f16)(v.z - (float)h2); lv[3] = (f16)(v.w - (float)h3);
    ((f16x4*)hi)[i] = hv;
    ((f16x4*)lo)[i] = lv;
}

// --- P: KV = concat(sp,ms) -> KVhi [b][2C][L] fp16  +  KVT_hi [b][L][2C] ---
__global__ __launch_bounds__(256) void p_kv(const float* __restrict__ sp,
                                            const float* __restrict__ ms,
                                            f16* __restrict__ kvhi,
                                            f16* __restrict__ kvt) {
    __shared__ __align__(16) f16 tile[64][68];
    const int b = blockIdx.z, c0 = blockIdx.y * 64, l0 = blockIdx.x * 64;
    const int t = threadIdx.x;
    const int r = t >> 2, q = t & 3;
    const float* src = (c0 + r < Cc)
        ? sp + ((size_t)b * Cc + c0 + r) * Ll
        : ms + ((size_t)b * Cc + (c0 + r - Cc)) * Ll;
    #pragma unroll
    for (int i = 0; i < 4; ++i) {
        int col = q * 16 + i * 4;
        float4 v = *(const float4*)(src + l0 + col);
        f16x4 hv; hv[0] = (f16)v.x; hv[1] = (f16)v.y; hv[2] = (f16)v.z; hv[3] = (f16)v.w;
        *(f16x4*)&kvhi[((size_t)b * KV2 + c0 + r) * Ll + l0 + col] = hv;
        *(f16x4*)&tile[r][col] = hv;
    }
    __syncthreads();
    const int ln = t >> 2;
    #pragma unroll
    for (int i = 0; i < 4; ++i) {
        int cc = q * 16 + i * 4;
        f16x4 o;
        o[0] = tile[cc + 0][ln]; o[1] = tile[cc + 1][ln];
        o[2] = tile[cc + 2][ln]; o[3] = tile[cc + 3][ln];
        *(f16x4*)&kvt[((size_t)b * Ll + l0 + ln) * KV2 + c0 + cc] = o;
    }
}

// --- Softmax over last dim of attn [B][C][KV2] fp32, writing attnT_hi
//     [B][KV2][C] fp16 (transposed, rounded). 16 rows per block. -----------
__global__ __launch_bounds__(256) void k2_softmax_t(const float* __restrict__ attn,
                                                    f16* __restrict__ attnT) {
    __shared__ float rmax[16], rinv[16];
    __shared__ __align__(16) f16 tile[16][68];
    const int b = blockIdx.y, c0 = blockIdx.x * 16;
    const int t = threadIdx.x, w = t >> 6, lane = t & 63;
    // phase 1: per-row max + expsum
    for (int rr = 0; rr < 4; ++rr) {
        int r = w * 4 + rr;
        const float4* p = (const float4*)(attn + ((size_t)b * Cc + c0 + r) * KV2);
        float4 v[4];
        float m = -3.4e38f;
        #pragma unroll
        for (int i = 0; i < 4; ++i) {
            v[i] = p[lane + 64 * i];
            m = fmaxf(m, fmaxf(fmaxf(v[i].x, v[i].y), fmaxf(v[i].z, v[i].w)));
        }
        #pragma unroll
        for (int off = 32; off; off >>= 1) m = fmaxf(m, __shfl_xor(m, off));
        float s = 0.f;
        #pragma unroll
        for (int i = 0; i < 4; ++i)
            s += __expf(v[i].x - m) + __expf(v[i].y - m) + __expf(v[i].z - m) + __expf(v[i].w - m);
        #pragma unroll
        for (int off = 32; off; off >>= 1) s += __shfl_xor(s, off);
        if (lane == 0) { rmax[r] = m; rinv[r] = 1.0f / s; }
    }
    __syncthreads();
    // phase 2: re-read, normalize, transpose through LDS, store fp16
    const int r2 = t >> 4, cn = (t & 15) * 4;
    const int n4 = t >> 2, q = t & 3;
    for (int nt = 0; nt < 16; ++nt) {
        float4 v = *(const float4*)(attn + ((size_t)b * Cc + c0 + r2) * KV2 + nt * 64 + cn);
        float m = rmax[r2], iv = rinv[r2];
        f16x4 hv;
        hv[0] = (f16)(__expf(v.x - m) * iv); hv[1] = (f16)(__expf(v.y - m) * iv);
        hv[2] = (f16)(__expf(v.z - m) * iv); hv[3] = (f16)(__expf(v.w - m) * iv);
        *(f16x4*)&tile[r2][cn] = hv;
        __syncthreads();
        f16x4 o;
        o[0] = tile[q * 4 + 0][n4]; o[1] = tile[q * 4 + 1][n4];
        o[2] = tile[q * 4 + 2][n4]; o[3] = tile[q * 4 + 3][n4];
        *(f16x4*)&attnT[((size_t)b * KV2 + nt * 64 + n4) * Cc + c0 + q * 4] = o;
        __syncthreads();
    }
}

// --- NT GEMM: D[b][m][n] = sum_k (Ahi+Alo)[b][m][k] * Bh[b][n][k] ---------
// 128x128 block, 4 waves of 64x64 (4x4 frags of 16x16x32 f16 MFMA), BK=32.
// EPI 0: fp32 out * (scale[0]/64)      (k1 logits)
// EPI 1: hi/lo fp16 out                (k3 W@attn -> attn2)
// EPI 2: fp32 out + bias[m]            (k4 final)
template<int KD, int NC, int EPI>
__global__ __launch_bounds__(256, 2) void gemm_nt(
    const f16* __restrict__ Ahi, const f16* __restrict__ Alo, size_t sA,
    const f16* __restrict__ Bh, size_t sB,
    const float* __restrict__ scale_ptr, const float* __restrict__ bias,
    float* __restrict__ Cf, f16* __restrict__ Chi, f16* __restrict__ Clo,
    size_t sC) {
    __shared__ __align__(16) f16 sAh[128][40];
    __shared__ __align__(16) f16 sAl[128][40];
    __shared__ __align__(16) f16 sBn[128][40];

    const int b = blockIdx.z, m0 = blockIdx.y * 128, n0 = blockIdx.x * 128;
    const int t = threadIdx.x;
    const int row = t >> 1, h = t & 1;
    const int w = t >> 6, lane = t & 63, quad = lane >> 4, lr = lane & 15;
    const int wm = (w & 1) * 64, wn = (w >> 1) * 64;

    const f16* gA  = Ahi + b * sA + (size_t)(m0 + row) * KD;
    const f16* gAl = Alo + b * sA + (size_t)(m0 + row) * KD;
    const f16* gB  = Bh  + b * sB + (size_t)(n0 + row) * KD;

    f32x4 acc[4][4];
    #pragma unroll
    for (int i = 0; i < 4; ++i)
        #pragma unroll
        for (int j = 0; j < 4; ++j) {
            acc[i][j][0] = 0.f; acc[i][j][1] = 0.f;
            acc[i][j][2] = 0.f; acc[i][j][3] = 0.f;
        }

    // register prefetch of tile 0
    f16x8 ra0 = *(const f16x8*)(gA + 8 * h);
    f16x8 ra1 = *(const f16x8*)(gA + 8 * h + 16);
    f16x8 rl0 = *(const f16x8*)(gAl + 8 * h);
    f16x8 rl1 = *(const f16x8*)(gAl + 8 * h + 16);
    f16x8 rb0 = *(const f16x8*)(gB + 8 * h);
    f16x8 rb1 = *(const f16x8*)(gB + 8 * h + 16);

    for (int k0 = 0; k0 < KD; k0 += 32) {
        __syncthreads();   // previous iteration's fragment reads complete
        *(f16x8*)&sAh[row][8 * h]      = ra0;
        *(f16x8*)&sAh[row][8 * h + 16] = ra1;
        *(f16x8*)&sAl[row][8 * h]      = rl0;
        *(f16x8*)&sAl[row][8 * h + 16] = rl1;
        *(f16x8*)&sBn[row][8 * h]      = rb0;
        *(f16x8*)&sBn[row][8 * h + 16] = rb1;
        __syncthreads();
        if (k0 + 32 < KD) {   // prefetch next tile; overlaps MFMA below
            ra0 = *(const f16x8*)(gA + k0 + 32 + 8 * h);
            ra1 = *(const f16x8*)(gA + k0 + 32 + 8 * h + 16);
            rl0 = *(const f16x8*)(gAl + k0 + 32 + 8 * h);
            rl1 = *(const f16x8*)(gAl + k0 + 32 + 8 * h + 16);
            rb0 = *(const f16x8*)(gB + k0 + 32 + 8 * h);
            rb1 = *(const f16x8*)(gB + k0 + 32 + 8 * h + 16);
        }
        f16x8 af[4], al[4], bf[4];
        #pragma unroll
        for (int i = 0; i < 4; ++i) {
            af[i] = *(const f16x8*)&sAh[wm + i * 16 + lr][8 * quad];
            al[i] = *(const f16x8*)&sAl[wm + i * 16 + lr][8 * quad];
        }
        #pragma unroll
        for (int j = 0; j < 4; ++j)
            bf[j] = *(const f16x8*)&sBn[wn + j * 16 + lr][8 * quad];
        #pragma unroll
        for (int i = 0; i < 4; ++i)
            #pragma unroll
            for (int j = 0; j < 4; ++j) {
                acc[i][j] = __builtin_amdgcn_mfma_f32_16x16x32_f16(af[i], bf[j], acc[i][j], 0, 0, 0);
                acc[i][j] = __builtin_amdgcn_mfma_f32_16x16x32_f16(al[i], bf[j], acc[i][j], 0, 0, 0);
            }
    }

    // epilogue: D[m][n]: n = lane&15 within 16-col frag, m = quad*4 + reg
    float alpha = 1.0f;
    if constexpr (EPI == 0) alpha = scale_ptr[0] * 0.015625f;  // scale * L^-0.5
    #pragma unroll
    for (int i = 0; i < 4; ++i)
        #pragma unroll
        for (int j = 0; j < 4; ++j) {
            const int n = n0 + wn + j * 16 + lr;
            #pragma unroll
            for (int r = 0; r < 4; ++r) {
                const int m = m0 + wm + i * 16 + quad * 4 + r;
                const size_t idx = b * sC + (size_t)m * NC + n;
                float v = acc[i][j][r];
                if constexpr (EPI == 0) {
                    Cf[idx] = alpha * v;
                } else if constexpr (EPI == 1) {
                    f16 hh = (f16)v;
                    Chi[idx] = hh;
                    Clo[idx] = (f16)(v - (float)hh);
                } else {
                    Cf[idx] = v + bias[m];
                }
            }
        }
}

// ===========================================================================
// FALLBACK PATH (round-1 fp32 kernels; used when ws_size < 244 MB)
// ===========================================================================
#define BM 64
#define BN 64
#define BK 32
#define PAD 4

__device__ __forceinline__ const float* kv_row(const float* __restrict__ sp,
                                               const float* __restrict__ ms,
                                               int b, int k) {
    return (k < Cc) ? (sp + ((size_t)b * Cc + k) * Ll)
                    : (ms + ((size_t)b * Cc + (k - Cc)) * Ll);
}

__global__ __launch_bounds__(256) void k1_logits(const float* __restrict__ x,
                                                 const float* __restrict__ sp,
                                                 const float* __restrict__ ms,
                                                 const float* __restrict__ scale,
                                                 float* __restrict__ attn) {
    __shared__ __align__(16) float As[BK][BM + PAD];
    __shared__ __align__(16) float Bs[BK][BN + PAD];
    const int b = blockIdx.z, m0 = blockIdx.y * BM, n0 = blockIdx.x * BN;
    const int t = threadIdx.x, tx = t & 15, ty = t >> 4, q = t & 7, r = t >> 3;
    const float alpha = scale[0] * (1.0f / 64.0f);
    const float* Abase = x + (size_t)b * Cc * Ll;
    float acc[4][4] = {};
    for (int k0 = 0; k0 < Ll; k0 += BK) {
        #pragma unroll
        for (int hh = 0; hh < 2; ++hh) {
            const int rw = r + 32 * hh;
            float4 v = *(const float4*)(Abase + (size_t)(m0 + rw) * Ll + k0 + 4 * q);
            As[4*q+0][rw] = v.x; As[4*q+1][rw] = v.y; As[4*q+2][rw] = v.z; As[4*q+3][rw] = v.w;
        }
        #pragma unroll
        for (int hh = 0; hh < 2; ++hh) {
            const int rw = r + 32 * hh;
            const float* Brow = kv_row(sp, ms, b, n0 + rw);
            float4 v = *(const float4*)(Brow + k0 + 4 * q);
            Bs[4*q+0][rw] = v.x; Bs[4*q+1][rw] = v.y; Bs[4*q+2][rw] = v.z; Bs[4*q+3][rw] = v.w;
        }
        __syncthreads();
        #pragma unroll
        for (int k = 0; k < BK; ++k) {
            float a[4], bb[4];
            *(float4*)a  = *(const float4*)&As[k][4 * ty];
            *(float4*)bb = *(const float4*)&Bs[k][4 * tx];
            #pragma unroll
            for (int i = 0; i < 4; ++i)
                #pragma unroll
                for (int j = 0; j < 4; ++j) acc[i][j] += a[i] * bb[j];
        }
        __syncthreads();
    }
    #pragma unroll
    for (int i = 0; i < 4; ++i) {
        const int m = m0 + 4 * ty + i;
        float4 o;
        o.x = alpha * acc[i][0]; o.y = alpha * acc[i][1];
        o.z = alpha * acc[i][2]; o.w = alpha * acc[i][3];
        *(float4*)(attn + ((size_t)b * Cc + m) * KV2 + n0 + 4 * tx) = o;
    }
}

__global__ __launch_bounds__(256) void k2_softmax(float* __restrict__ attn) {
    float* p = attn + (size_t)blockIdx.x * KV2;
    const int t = threadIdx.x, lane = t & 63, wv = t >> 6;
    float4 v = ((const float4*)p)[t];
    float m = fmaxf(fmaxf(v.x, v.y), fmaxf(v.z, v.w));
    #pragma unroll
    for (int off = 32; off; off >>= 1) m = fmaxf(m, __shfl_down(m, off));
    __shared__ float redm[4];
    if (lane == 0) redm[wv] = m;
    __syncthreads();
    m = fmaxf(fmaxf(redm[0], redm[1]), fmaxf(redm[2], redm[3]));
    v.x = __expf(v.x - m); v.y = __expf(v.y - m);
    v.z = __expf(v.z - m); v.w = __expf(v.w - m);
    float s = v.x + v.y + v.z + v.w;
    #pragma unroll
    for (int off = 32; off; off >>= 1) s += __shfl_down(s, off);
    __shared__ float reds[4];
    if (lane == 0) reds[wv] = s;
    __syncthreads();
    s = reds[0] + reds[1] + reds[2] + reds[3];
    const float inv = 1.0f / s;
    v.x *= inv; v.y *= inv; v.z *= inv; v.w *= inv;
    ((float4*)p)[t] = v;
}

__global__ __launch_bounds__(256) void k3_wattn(const float* __restrict__ W,
                                                const float* __restrict__ attn,
                                                float* __restrict__ attn2) {
    __shared__ __align__(16) float As[BK][BM + PAD];
    __shared__ __align__(16) float Bs[BK][BN];
    const int b = blockIdx.z, m0 = blockIdx.y * BM, n0 = blockIdx.x * BN;
    const int t = threadIdx.x, tx = t & 15, ty = t >> 4;
    const int q = t & 7, r = t >> 3, c4 = t & 15, kr = t >> 4;
    const float* Bbase = attn + (size_t)b * Cc * KV2;
    float acc[4][4] = {};
    for (int k0 = 0; k0 < Cc; k0 += BK) {
        #pragma unroll
        for (int hh = 0; hh < 2; ++hh) {
            const int rw = r + 32 * hh;
            float4 v = *(const float4*)(W + (size_t)(m0 + rw) * Cc + k0 + 4 * q);
            As[4*q+0][rw] = v.x; As[4*q+1][rw] = v.y; As[4*q+2][rw] = v.z; As[4*q+3][rw] = v.w;
        }
        #pragma unroll
        for (int hh = 0; hh < 2; ++hh) {
            const int k = kr + 16 * hh;
            float4 v = *(const float4*)(Bbase + (size_t)(k0 + k) * KV2 + n0 + 4 * c4);
            *(float4*)&Bs[k][4 * c4] = v;
        }
        __syncthreads();
        #pragma unroll
        for (int k = 0; k < BK; ++k) {
            float a[4], bb[4];
            *(float4*)a  = *(const float4*)&As[k][4 * ty];
            *(float4*)bb = *(const float4*)&Bs[k][4 * tx];
            #pragma unroll
            for (int i = 0; i < 4; ++i)
                #pragma unroll
                for (int j = 0; j < 4; ++j) acc[i][j] += a[i] * bb[j];
        }
        __syncthreads();
    }
    #pragma unroll
    for (int i = 0; i < 4; ++i) {
        const int m = m0 + 4 * ty + i;
        float4 o;
        o.x = acc[i][0]; o.y = acc[i][1]; o.z = acc[i][2]; o.w = acc[i][3];
        *(float4*)(attn2 + ((size_t)b * Cc + m) * KV2 + n0 + 4 * tx) = o;
    }
}

__global__ __launch_bounds__(256) void k4_out(const float* __restrict__ attn2,
                                              const float* __restrict__ sp,
                                              const float* __restrict__ ms,
                                              const float* __restrict__ bias,
                                              float* __restrict__ out) {
    __shared__ __align__(16) float As[BK][BM + PAD];
    __shared__ __align__(16) float Bs[BK][BN];
    const int b = blockIdx.z, m0 = blockIdx.y * BM, n0 = blockIdx.x * BN;
    const int t = threadIdx.x, tx = t & 15, ty = t >> 4;
    const int q = t & 7, r = t >> 3, c4 = t & 15, kr = t >> 4;
    const float* Abase = attn2 + (size_t)b * Cc * KV2;
    float acc[4][4] = {};
    for (int k0 = 0; k0 < KV2; k0 += BK) {
        #pragma unroll
        for (int hh = 0; hh < 2; ++hh) {
            const int rw = r + 32 * hh;
            float4 v = *(const float4*)(Abase + (size_t)(m0 + rw) * KV2 + k0 + 4 * q);
            As[4*q+0][rw] = v.x; As[4*q+1][rw] = v.y; As[4*q+2][rw] = v.z; As[4*q+3][rw] = v.w;
        }
        #pragma unroll
        for (int hh = 0; hh < 2; ++hh) {
            const int k = kr + 16 * hh;
            const float* Brow = kv_row(sp, ms, b, k0 + k);
            float4 v = *(const float4*)(Brow + n0 + 4 * c4);
            *(float4*)&Bs[k][4 * c4] = v;
        }
        __syncthreads();
        #pragma unroll
        for (int k = 0; k < BK; ++k) {
            float a[4], bb[4];
            *(float4*)a  = *(const float4*)&As[k][4 * ty];
            *(float4*)bb = *(const float4*)&Bs[k][4 * tx];
            #pragma unroll
            for (int i = 0; i < 4; ++i)
                #pragma unroll
                for (int j = 0; j < 4; ++j) acc[i][j] += a[i] * bb[j];
        }
        __syncthreads();
    }
    #pragma unroll
    for (int i = 0; i < 4; ++i) {
        const int m = m0 + 4 * ty + i;
        const float bm = bias[m];
        float4 o;
        o.x = acc[i][0] + bm; o.y = acc[i][1] + bm;
        o.z = acc[i][2] + bm; o.w = acc[i][3] + bm;
        *(float4*)(out + ((size_t)b * Cc + m) * Ll + n0 + 4 * tx) = o;
    }
}

// ===========================================================================
extern "C" void kernel_launch(void* const* d_in, const int* in_sizes, int n_in,
                              void* d_out, int out_size, void* d_ws, size_t ws_size,
                              hipStream_t stream) {
    const float* x     = (const float*)d_in[0];
    const float* sp    = (const float*)d_in[1];
    const float* ms    = (const float*)d_in[2];
    const float* scale = (const float*)d_in[3];
    const float* W     = (const float*)d_in[4];
    const float* bias  = (const float*)d_in[5];
    float* out = (float*)d_out;

    const size_t NEED = 244318208;  // bytes for fp16-split pipeline
    if (ws_size >= NEED) {
        char* ws = (char*)d_ws;
        f16*   Xhi   = (f16*)ws;                          // 33,554,432
        f16*   Xlo   = (f16*)(ws + 33554432);             // 33,554,432
        f16*   KVhi  = (f16*)(ws + 67108864);             // 67,108,864
        f16*   KVT   = (f16*)(ws + 134217728);            // 67,108,864
        f16*   Whi   = (f16*)(ws + 201326592);            //    524,288
        f16*   Wlo   = (f16*)(ws + 201850880);            //    524,288
        float* attn  = (float*)(ws + 202375168);          // 16,777,216
        f16*   attnT = (f16*)(ws + 219152384);            //  8,388,608
        f16*   A2hi  = (f16*)(ws + 227540992);            //  8,388,608
        f16*   A2lo  = (f16*)(ws + 235929600);            //  8,388,608

        dim3 blk(256);
        p_split<<<dim3(16384), blk, 0, stream>>>(x, Xhi, Xlo, Bq * Cc * Ll / 4);
        p_split<<<dim3(256),   blk, 0, stream>>>(W, Whi, Wlo, Cc * Cc / 4);
        p_kv   <<<dim3(Ll / 64, KV2 / 64, Bq), blk, 0, stream>>>(sp, ms, KVhi, KVT);

        gemm_nt<Ll, KV2, 0><<<dim3(KV2 / 128, Cc / 128, Bq), blk, 0, stream>>>(
            Xhi, Xlo, (size_t)Cc * Ll, KVhi, (size_t)KV2 * Ll,
            scale, nullptr, attn, nullptr, nullptr, (size_t)Cc * KV2);

        k2_softmax_t<<<dim3(Cc / 16, Bq), blk, 0, stream>>>(attn, attnT);

        gemm_nt<Cc, KV2, 1><<<dim3(KV2 / 128, Cc / 128, Bq), blk, 0, stream>>>(
            Whi, Wlo, (size_t)0, attnT, (size_t)KV2 * Cc,
            nullptr, nullptr, nullptr, A2hi, A2lo, (size_t)Cc * KV2);

        gemm_nt<KV2, Ll, 2><<<dim3(Ll / 128, Cc / 128, Bq), blk, 0, stream>>>(
            A2hi, A2lo, (size_t)Cc * KV2, KVT, (size_t)Ll * KV2,
            nullptr, bias, out, nullptr, nullptr, (size_t)Cc * Ll);
    } else {
        // fp32 fallback (round-1 path), needs 33.6 MB
        float* attn  = (float*)d_ws;
        float* attn2 = attn + (size_t)Bq * Cc * KV2;
        dim3 blk(256);
        k1_logits <<<dim3(KV2 / BN, Cc / BM, Bq), blk, 0, stream>>>(x, sp, ms, scale, attn);
        k2_softmax<<<dim3(Bq * Cc),               blk, 0, stream>>>(attn);
        k3_wattn  <<<dim3(KV2 / BN, Cc / BM, Bq), blk, 0, stream>>>(W, attn, attn2);
        k4_out    <<<dim3(Ll / BN, Cc / BM, Bq), blk, 0, stream>>>(attn2, sp, ms, bias, out);
    }
}

// Round 3
// 401.877 us; speedup vs baseline: 2.8910x; 1.1824x over previous
//
#include <hip/hip_runtime.h>

#define Bq   8
#define Cc   512
#define Ll   4096   // H*W
#define KV2  1024   // 2C
#define KS   4      // split-K factor for k1
#define KSL  (Ll / KS)

typedef _Float16 f16;
typedef __attribute__((ext_vector_type(4))) _Float16 f16x4;
typedef __attribute__((ext_vector_type(8))) _Float16 f16x8;
typedef __attribute__((ext_vector_type(4))) float    f32x4;

// --- fp32 pair -> f16 hi/lo split helper ----------------------------------
__device__ __forceinline__ void cvt8(const float4& u, const float4& v,
                                     f16x8& hi, f16x8& lo) {
    float a[8] = {u.x, u.y, u.z, u.w, v.x, v.y, v.z, v.w};
    #pragma unroll
    for (int i = 0; i < 8; ++i) {
        f16 hh = (f16)a[i];
        hi[i] = hh;
        lo[i] = (f16)(a[i] - (float)hh);
    }
}

// ===========================================================================
// P: KV = concat(sp,ms) -> KVhi [b][2C][L] f16 + KVT [b][L][2C] f16.
// Transpose via fp32 LDS tile, pad 65 => conflict-free both phases.
// ===========================================================================
__global__ __launch_bounds__(256) void p_kv(const float* __restrict__ sp,
                                            const float* __restrict__ ms,
                                            f16* __restrict__ kvhi,
                                            f16* __restrict__ kvt) {
    __shared__ float tile[64][65];
    const int b = blockIdx.z, c0 = blockIdx.y * 64, l0 = blockIdx.x * 64;
    const int t = threadIdx.x;
    const int r = t >> 2, q = t & 3;
    const float* src = (c0 + r < Cc)
        ? sp + ((size_t)b * Cc + c0 + r) * Ll
        : ms + ((size_t)b * Cc + (c0 + r - Cc)) * Ll;
    #pragma unroll
    for (int i = 0; i < 4; ++i) {
        int col = q * 16 + i * 4;
        float4 v = *(const float4*)(src + l0 + col);
        f16x4 hv; hv[0] = (f16)v.x; hv[1] = (f16)v.y; hv[2] = (f16)v.z; hv[3] = (f16)v.w;
        *(f16x4*)&kvhi[((size_t)b * KV2 + c0 + r) * Ll + l0 + col] = hv;
        tile[r][col] = v.x; tile[r][col + 1] = v.y;
        tile[r][col + 2] = v.z; tile[r][col + 3] = v.w;
    }
    __syncthreads();
    const int ln = t >> 3, q8 = t & 7;
    #pragma unroll
    for (int p = 0; p < 2; ++p) {
        const int l = ln + 32 * p;
        f16x8 o;
        #pragma unroll
        for (int j = 0; j < 8; ++j) o[j] = (f16)tile[q8 * 8 + j][l];
        *(f16x8*)&kvt[((size_t)b * Ll + l0 + l) * KV2 + c0 + q8 * 8] = o;
    }
}

// --- W fp32 -> hi/lo fp16 (small) -----------------------------------------
__global__ __launch_bounds__(256) void p_split(const float* __restrict__ in,
                                               f16* __restrict__ hi,
                                               f16* __restrict__ lo, int n4) {
    int i = blockIdx.x * 256 + threadIdx.x;
    if (i >= n4) return;
    float4 v = ((const float4*)in)[i];
    f16 h0 = (f16)v.x, h1 = (f16)v.y, h2 = (f16)v.z, h3 = (f16)v.w;
    f16x4 hv; hv[0] = h0; hv[1] = h1; hv[2] = h2; hv[3] = h3;
    f16x4 lv;
    lv[0] = (f16)(v.x - (float)h0); lv[1] = (f16)(v.y - (float)h1);
    lv[2] = (f16)(v.z - (float)h2); lv[3] = (f16)(v.w - (float)h3);
    ((f16x4*)hi)[i] = hv;
    ((f16x4*)lo)[i] = lv;
}

// ===========================================================================
// K1: split-K NT gemm with fused fp32->hi/lo staging of A = x.
// attnP[s][b][m][n] = alpha * sum_{k in slice s} x[b][m][k] * KVhi[b][n][k]
// grid (KV2/128, Cc/128, Bq*KS)
// ===========================================================================
__global__ __launch_bounds__(256, 2) void gemm_k1(const float* __restrict__ x,
                                                  const f16* __restrict__ kvhi,
                                                  const float* __restrict__ scale_ptr,
                                                  float* __restrict__ attnP) {
    __shared__ __align__(16) f16 sAh[128][40];
    __shared__ __align__(16) f16 sAl[128][40];
    __shared__ __align__(16) f16 sBn[128][40];

    const int z = blockIdx.z, b = z >> 2, s = z & 3;
    const int m0 = blockIdx.y * 128, n0 = blockIdx.x * 128;
    const int t = threadIdx.x;
    const int row = t >> 1, h = t & 1;
    const int w = t >> 6, lane = t & 63, quad = lane >> 4, lr = lane & 15;
    const int wm = (w & 1) * 64, wn = (w >> 1) * 64;

    const float* gA = x    + ((size_t)b * Cc  + m0 + row) * Ll + s * KSL;
    const f16*   gB = kvhi + ((size_t)b * KV2 + n0 + row) * Ll + s * KSL;

    f32x4 acc[4][4];
    #pragma unroll
    for (int i = 0; i < 4; ++i)
        #pragma unroll
        for (int j = 0; j < 4; ++j) {
            acc[i][j][0] = 0.f; acc[i][j][1] = 0.f;
            acc[i][j][2] = 0.f; acc[i][j][3] = 0.f;
        }

    float4 a0 = *(const float4*)(gA + 16 * h);
    float4 a1 = *(const float4*)(gA + 16 * h + 4);
    float4 a2 = *(const float4*)(gA + 16 * h + 8);
    float4 a3 = *(const float4*)(gA + 16 * h + 12);
    f16x8 rb0 = *(const f16x8*)(gB + 8 * h);
    f16x8 rb1 = *(const f16x8*)(gB + 8 * h + 16);

    for (int k0 = 0; k0 < KSL; k0 += 32) {
        __syncthreads();
        f16x8 ah0, al0, ah1, al1;
        cvt8(a0, a1, ah0, al0);
        cvt8(a2, a3, ah1, al1);
        *(f16x8*)&sAh[row][16 * h]     = ah0;
        *(f16x8*)&sAh[row][16 * h + 8] = ah1;
        *(f16x8*)&sAl[row][16 * h]     = al0;
        *(f16x8*)&sAl[row][16 * h + 8] = al1;
        *(f16x8*)&sBn[row][8 * h]      = rb0;
        *(f16x8*)&sBn[row][8 * h + 16] = rb1;
        __syncthreads();
        if (k0 + 32 < KSL) {
            a0 = *(const float4*)(gA + k0 + 32 + 16 * h);
            a1 = *(const float4*)(gA + k0 + 32 + 16 * h + 4);
            a2 = *(const float4*)(gA + k0 + 32 + 16 * h + 8);
            a3 = *(const float4*)(gA + k0 + 32 + 16 * h + 12);
            rb0 = *(const f16x8*)(gB + k0 + 32 + 8 * h);
            rb1 = *(const f16x8*)(gB + k0 + 32 + 8 * h + 16);
        }
        f16x8 af[4], al[4], bf[4];
        #pragma unroll
        for (int i = 0; i < 4; ++i) {
            af[i] = *(const f16x8*)&sAh[wm + i * 16 + lr][8 * quad];
            al[i] = *(const f16x8*)&sAl[wm + i * 16 + lr][8 * quad];
        }
        #pragma unroll
        for (int j = 0; j < 4; ++j)
            bf[j] = *(const f16x8*)&sBn[wn + j * 16 + lr][8 * quad];
        #pragma unroll
        for (int i = 0; i < 4; ++i)
            #pragma unroll
            for (int j = 0; j < 4; ++j) {
                acc[i][j] = __builtin_amdgcn_mfma_f32_16x16x32_f16(af[i], bf[j], acc[i][j], 0, 0, 0);
                acc[i][j] = __builtin_amdgcn_mfma_f32_16x16x32_f16(al[i], bf[j], acc[i][j], 0, 0, 0);
            }
    }

    const float alpha = scale_ptr[0] * 0.015625f;
    float* Cs = attnP + (size_t)s * Bq * Cc * KV2 + (size_t)b * Cc * KV2;
    #pragma unroll
    for (int i = 0; i < 4; ++i)
        #pragma unroll
        for (int j = 0; j < 4; ++j) {
            const int n = n0 + wn + j * 16 + lr;
            #pragma unroll
            for (int r = 0; r < 4; ++r) {
                const int m = m0 + wm + i * 16 + quad * 4 + r;
                Cs[(size_t)m * KV2 + n] = alpha * acc[i][j][r];
            }
        }
}

// ===========================================================================
// K2: sum KS partials, softmax over last dim (1024), write attnT [b][n][c] f16
// ===========================================================================
__global__ __launch_bounds__(256) void k2_softmax_t(const float* __restrict__ attnP,
                                                    f16* __restrict__ attnT) {
    __shared__ float rmax[16], rinv[16];
    __shared__ __align__(16) f16 tile[16][68];
    const int b = blockIdx.y, c0 = blockIdx.x * 16;
    const int t = threadIdx.x, w = t >> 6, lane = t & 63;
    const size_t sS = (size_t)Bq * Cc * KV2;

    for (int rr = 0; rr < 4; ++rr) {
        const int r = w * 4 + rr;
        const float* base = attnP + ((size_t)b * Cc + c0 + r) * KV2;
        float4 v[4];
        float m = -3.4e38f;
        #pragma unroll
        for (int i = 0; i < 4; ++i) {
            v[i] = ((const float4*)base)[lane + 64 * i];
            #pragma unroll
            for (int s = 1; s < KS; ++s) {
                float4 u = ((const float4*)(base + s * sS))[lane + 64 * i];
                v[i].x += u.x; v[i].y += u.y; v[i].z += u.z; v[i].w += u.w;
            }
            m = fmaxf(m, fmaxf(fmaxf(v[i].x, v[i].y), fmaxf(v[i].z, v[i].w)));
        }
        #pragma unroll
        for (int off = 32; off; off >>= 1) m = fmaxf(m, __shfl_xor(m, off));
        float s = 0.f;
        #pragma unroll
        for (int i = 0; i < 4; ++i)
            s += __expf(v[i].x - m) + __expf(v[i].y - m) + __expf(v[i].z - m) + __expf(v[i].w - m);
        #pragma unroll
        for (int off = 32; off; off >>= 1) s += __shfl_xor(s, off);
        if (lane == 0) { rmax[r] = m; rinv[r] = 1.0f / s; }
    }
    __syncthreads();

    const int r2 = t >> 4, cn = (t & 15) * 4;
    const int n4 = t >> 2, q = t & 3;
    for (int nt = 0; nt < 16; ++nt) {
        const float* base = attnP + ((size_t)b * Cc + c0 + r2) * KV2 + nt * 64 + cn;
        float4 v = *(const float4*)base;
        #pragma unroll
        for (int s = 1; s < KS; ++s) {
            float4 u = *(const float4*)(base + s * sS);
            v.x += u.x; v.y += u.y; v.z += u.z; v.w += u.w;
        }
        const float m = rmax[r2], iv = rinv[r2];
        f16x4 hv;
        hv[0] = (f16)(__expf(v.x - m) * iv); hv[1] = (f16)(__expf(v.y - m) * iv);
        hv[2] = (f16)(__expf(v.z - m) * iv); hv[3] = (f16)(__expf(v.w - m) * iv);
        *(f16x4*)&tile[r2][cn] = hv;
        __syncthreads();
        f16x4 o;
        o[0] = tile[q * 4 + 0][n4]; o[1] = tile[q * 4 + 1][n4];
        o[2] = tile[q * 4 + 2][n4]; o[3] = tile[q * 4 + 3][n4];
        *(f16x4*)&attnT[((size_t)b * KV2 + nt * 64 + n4) * Cc + c0 + q * 4] = o;
        __syncthreads();
    }
}

// ===========================================================================
// Generic NT GEMM (f16 inputs). LO: A has a lo-term. EPI 1: f16 out (k3).
// EPI 2: fp32 out + bias[m] (k4).
// ===========================================================================
template<int KD, int NC, int EPI, bool LO>
__global__ __launch_bounds__(256, 2) void gemm_nt(
    const f16* __restrict__ Ah, const f16* __restrict__ Al, size_t sA,
    const f16* __restrict__ Bh, size_t sB,
    const float* __restrict__ bias,
    float* __restrict__ Cf, f16* __restrict__ Chi, size_t sC) {
    __shared__ __align__(16) f16 sAh[128][40];
    __shared__ __align__(16) f16 sAl[LO ? 128 : 1][40];
    __shared__ __align__(16) f16 sBn[128][40];

    const int b = blockIdx.z, m0 = blockIdx.y * 128, n0 = blockIdx.x * 128;
    const int t = threadIdx.x;
    const int row = t >> 1, h = t & 1;
    const int w = t >> 6, lane = t & 63, quad = lane >> 4, lr = lane & 15;
    const int wm = (w & 1) * 64, wn = (w >> 1) * 64;

    const f16* gA  = Ah + b * sA + (size_t)(m0 + row) * KD;
    const f16* gAl = LO ? (Al + b * sA + (size_t)(m0 + row) * KD) : nullptr;
    const f16* gB  = Bh + b * sB + (size_t)(n0 + row) * KD;

    f32x4 acc[4][4];
    #pragma unroll
    for (int i = 0; i < 4; ++i)
        #pragma unroll
        for (int j = 0; j < 4; ++j) {
            acc[i][j][0] = 0.f; acc[i][j][1] = 0.f;
            acc[i][j][2] = 0.f; acc[i][j][3] = 0.f;
        }

    f16x8 ra0 = *(const f16x8*)(gA + 8 * h);
    f16x8 ra1 = *(const f16x8*)(gA + 8 * h + 16);
    f16x8 rl0, rl1;
    if constexpr (LO) {
        rl0 = *(const f16x8*)(gAl + 8 * h);
        rl1 = *(const f16x8*)(gAl + 8 * h + 16);
    }
    f16x8 rb0 = *(const f16x8*)(gB + 8 * h);
    f16x8 rb1 = *(const f16x8*)(gB + 8 * h + 16);

    for (int k0 = 0; k0 < KD; k0 += 32) {
        __syncthreads();
        *(f16x8*)&sAh[row][8 * h]      = ra0;
        *(f16x8*)&sAh[row][8 * h + 16] = ra1;
        if constexpr (LO) {
            *(f16x8*)&sAl[row][8 * h]      = rl0;
            *(f16x8*)&sAl[row][8 * h + 16] = rl1;
        }
        *(f16x8*)&sBn[row][8 * h]      = rb0;
        *(f16x8*)&sBn[row][8 * h + 16] = rb1;
        __syncthreads();
        if (k0 + 32 < KD) {
            ra0 = *(const f16x8*)(gA + k0 + 32 + 8 * h);
            ra1 = *(const f16x8*)(gA + k0 + 32 + 8 * h + 16);
            if constexpr (LO) {
                rl0 = *(const f16x8*)(gAl + k0 + 32 + 8 * h);
                rl1 = *(const f16x8*)(gAl + k0 + 32 + 8 * h + 16);
            }
            rb0 = *(const f16x8*)(gB + k0 + 32 + 8 * h);
            rb1 = *(const f16x8*)(gB + k0 + 32 + 8 * h + 16);
        }
        f16x8 af[4], alf[4], bf[4];
        #pragma unroll
        for (int i = 0; i < 4; ++i) {
            af[i] = *(const f16x8*)&sAh[wm + i * 16 + lr][8 * quad];
            if constexpr (LO) alf[i] = *(const f16x8*)&sAl[wm + i * 16 + lr][8 * quad];
        }
        #pragma unroll
        for (int j = 0; j < 4; ++j)
            bf[j] = *(const f16x8*)&sBn[wn + j * 16 + lr][8 * quad];
        #pragma unroll
        for (int i = 0; i < 4; ++i)
            #pragma unroll
            for (int j = 0; j < 4; ++j) {
                acc[i][j] = __builtin_amdgcn_mfma_f32_16x16x32_f16(af[i], bf[j], acc[i][j], 0, 0, 0);
                if constexpr (LO)
                    acc[i][j] = __builtin_amdgcn_mfma_f32_16x16x32_f16(alf[i], bf[j], acc[i][j], 0, 0, 0);
            }
    }

    #pragma unroll
    for (int i = 0; i < 4; ++i)
        #pragma unroll
        for (int j = 0; j < 4; ++j) {
            const int n = n0 + wn + j * 16 + lr;
            #pragma unroll
            for (int r = 0; r < 4; ++r) {
                const int m = m0 + wm + i * 16 + quad * 4 + r;
                const size_t idx = b * sC + (size_t)m * NC + n;
                const float v = acc[i][j][r];
                if constexpr (EPI == 1) Chi[idx] = (f16)v;
                else                    Cf[idx] = v + bias[m];
            }
        }
}

// ===========================================================================
// FALLBACK PATH (fp32, needs only 33.6 MB)
// ===========================================================================
#define BM 64
#define BN 64
#define BK 32
#define PAD 4

__device__ __forceinline__ const float* kv_row(const float* __restrict__ sp,
                                               const float* __restrict__ ms,
                                               int b, int k) {
    return (k < Cc) ? (sp + ((size_t)b * Cc + k) * Ll)
                    : (ms + ((size_t)b * Cc + (k - Cc)) * Ll);
}

__global__ __launch_bounds__(256) void k1_logits(const float* __restrict__ x,
                                                 const float* __restrict__ sp,
                                                 const float* __restrict__ ms,
                                                 const float* __restrict__ scale,
                                                 float* __restrict__ attn) {
    __shared__ __align__(16) float As[BK][BM + PAD];
    __shared__ __align__(16) float Bs[BK][BN + PAD];
    const int b = blockIdx.z, m0 = blockIdx.y * BM, n0 = blockIdx.x * BN;
    const int t = threadIdx.x, tx = t & 15, ty = t >> 4, q = t & 7, r = t >> 3;
    const float alpha = scale[0] * (1.0f / 64.0f);
    const float* Abase = x + (size_t)b * Cc * Ll;
    float acc[4][4] = {};
    for (int k0 = 0; k0 < Ll; k0 += BK) {
        #pragma unroll
        for (int hh = 0; hh < 2; ++hh) {
            const int rw = r + 32 * hh;
            float4 v = *(const float4*)(Abase + (size_t)(m0 + rw) * Ll + k0 + 4 * q);
            As[4*q+0][rw] = v.x; As[4*q+1][rw] = v.y; As[4*q+2][rw] = v.z; As[4*q+3][rw] = v.w;
        }
        #pragma unroll
        for (int hh = 0; hh < 2; ++hh) {
            const int rw = r + 32 * hh;
            const float* Brow = kv_row(sp, ms, b, n0 + rw);
            float4 v = *(const float4*)(Brow + k0 + 4 * q);
            Bs[4*q+0][rw] = v.x; Bs[4*q+1][rw] = v.y; Bs[4*q+2][rw] = v.z; Bs[4*q+3][rw] = v.w;
        }
        __syncthreads();
        #pragma unroll
        for (int k = 0; k < BK; ++k) {
            float a[4], bb[4];
            *(float4*)a  = *(const float4*)&As[k][4 * ty];
            *(float4*)bb = *(const float4*)&Bs[k][4 * tx];
            #pragma unroll
            for (int i = 0; i < 4; ++i)
                #pragma unroll
                for (int j = 0; j < 4; ++j) acc[i][j] += a[i] * bb[j];
        }
        __syncthreads();
    }
    #pragma unroll
    for (int i = 0; i < 4; ++i) {
        const int m = m0 + 4 * ty + i;
        float4 o;
        o.x = alpha * acc[i][0]; o.y = alpha * acc[i][1];
        o.z = alpha * acc[i][2]; o.w = alpha * acc[i][3];
        *(float4*)(attn + ((size_t)b * Cc + m) * KV2 + n0 + 4 * tx) = o;
    }
}

__global__ __launch_bounds__(256) void k2_softmax(float* __restrict__ attn) {
    float* p = attn + (size_t)blockIdx.x * KV2;
    const int t = threadIdx.x, lane = t & 63, wv = t >> 6;
    float4 v = ((const float4*)p)[t];
    float m = fmaxf(fmaxf(v.x, v.y), fmaxf(v.z, v.w));
    #pragma unroll
    for (int off = 32; off; off >>= 1) m = fmaxf(m, __shfl_down(m, off));
    __shared__ float redm[4];
    if (lane == 0) redm[wv] = m;
    __syncthreads();
    m = fmaxf(fmaxf(redm[0], redm[1]), fmaxf(redm[2], redm[3]));
    v.x = __expf(v.x - m); v.y = __expf(v.y - m);
    v.z = __expf(v.z - m); v.w = __expf(v.w - m);
    float s = v.x + v.y + v.z + v.w;
    #pragma unroll
    for (int off = 32; off; off >>= 1) s += __shfl_down(s, off);
    __shared__ float reds[4];
    if (lane == 0) reds[wv] = s;
    __syncthreads();
    s = reds[0] + reds[1] + reds[2] + reds[3];
    const float inv = 1.0f / s;
    v.x *= inv; v.y *= inv; v.z *= inv; v.w *= inv;
    ((float4*)p)[t] = v;
}

__global__ __launch_bounds__(256) void k3_wattn(const float* __restrict__ W,
                                                const float* __restrict__ attn,
                                                float* __restrict__ attn2) {
    __shared__ __align__(16) float As[BK][BM + PAD];
    __shared__ __align__(16) float Bs[BK][BN];
    const int b = blockIdx.z, m0 = blockIdx.y * BM, n0 = blockIdx.x * BN;
    const int t = threadIdx.x, tx = t & 15, ty = t >> 4;
    const int q = t & 7, r = t >> 3, c4 = t & 15, kr = t >> 4;
    const float* Bbase = attn + (size_t)b * Cc * KV2;
    float acc[4][4] = {};
    for (int k0 = 0; k0 < Cc; k0 += BK) {
        #pragma unroll
        for (int hh = 0; hh < 2; ++hh) {
            const int rw = r + 32 * hh;
            float4 v = *(const float4*)(W + (size_t)(m0 + rw) * Cc + k0 + 4 * q);
            As[4*q+0][rw] = v.x; As[4*q+1][rw] = v.y; As[4*q+2][rw] = v.z; As[4*q+3][rw] = v.w;
        }
        #pragma unroll
        for (int hh = 0; hh < 2; ++hh) {
            const int k = kr + 16 * hh;
            float4 v = *(const float4*)(Bbase + (size_t)(k0 + k) * KV2 + n0 + 4 * c4);
            *(float4*)&Bs[k][4 * c4] = v;
        }
        __syncthreads();
        #pragma unroll
        for (int k = 0; k < BK; ++k) {
            float a[4], bb[4];
            *(float4*)a  = *(const float4*)&As[k][4 * ty];
            *(float4*)bb = *(const float4*)&Bs[k][4 * tx];
            #pragma unroll
            for (int i = 0; i < 4; ++i)
                #pragma unroll
                for (int j = 0; j < 4; ++j) acc[i][j] += a[i] * bb[j];
        }
        __syncthreads();
    }
    #pragma unroll
    for (int i = 0; i < 4; ++i) {
        const int m = m0 + 4 * ty + i;
        float4 o;
        o.x = acc[i][0]; o.y = acc[i][1]; o.z = acc[i][2]; o.w = acc[i][3];
        *(float4*)(attn2 + ((size_t)b * Cc + m) * KV2 + n0 + 4 * tx) = o;
    }
}

__global__ __launch_bounds__(256) void k4_out(const float* __restrict__ attn2,
                                              const float* __restrict__ sp,
                                              const float* __restrict__ ms,
                                              const float* __restrict__ bias,
                                              float* __restrict__ out) {
    __shared__ __align__(16) float As[BK][BM + PAD];
    __shared__ __align__(16) float Bs[BK][BN];
    const int b = blockIdx.z, m0 = blockIdx.y * BM, n0 = blockIdx.x * BN;
    const int t = threadIdx.x, tx = t & 15, ty = t >> 4;
    const int q = t & 7, r = t >> 3, c4 = t & 15, kr = t >> 4;
    const float* Abase = attn2 + (size_t)b * Cc * KV2;
    float acc[4][4] = {};
    for (int k0 = 0; k0 < KV2; k0 += BK) {
        #pragma unroll
        for (int hh = 0; hh < 2; ++hh) {
            const int rw = r + 32 * hh;
            float4 v = *(const float4*)(Abase + (size_t)(m0 + rw) * KV2 + k0 + 4 * q);
            As[4*q+0][rw] = v.x; As[4*q+1][rw] = v.y; As[4*q+2][rw] = v.z; As[4*q+3][rw] = v.w;
        }
        #pragma unroll
        for (int hh = 0; hh < 2; ++hh) {
            const int k = kr + 16 * hh;
            const float* Brow = kv_row(sp, ms, b, k0 + k);
            float4 v = *(const float4*)(Brow + n0 + 4 * c4);
            *(float4*)&Bs[k][4 * c4] = v;
        }
        __syncthreads();
        #pragma unroll
        for (int k = 0; k < BK; ++k) {
            float a[4], bb[4];
            *(float4*)a  = *(const float4*)&As[k][4 * ty];
            *(float4*)bb = *(const float4*)&Bs[k][4 * tx];
            #pragma unroll
            for (int i = 0; i < 4; ++i)
                #pragma unroll
                for (int j = 0; j < 4; ++j) acc[i][j] += a[i] * bb[j];
        }
        __syncthreads();
    }
    #pragma unroll
    for (int i = 0; i < 4; ++i) {
        const int m = m0 + 4 * ty + i;
        const float bm = bias[m];
        float4 o;
        o.x = acc[i][0] + bm; o.y = acc[i][1] + bm;
        o.z = acc[i][2] + bm; o.w = acc[i][3] + bm;
        *(float4*)(out + ((size_t)b * Cc + m) * Ll + n0 + 4 * tx) = o;
    }
}

// ===========================================================================
extern "C" void kernel_launch(void* const* d_in, const int* in_sizes, int n_in,
                              void* d_out, int out_size, void* d_ws, size_t ws_size,
                              hipStream_t stream) {
    const float* x     = (const float*)d_in[0];
    const float* sp    = (const float*)d_in[1];
    const float* ms    = (const float*)d_in[2];
    const float* scale = (const float*)d_in[3];
    const float* W     = (const float*)d_in[4];
    const float* bias  = (const float*)d_in[5];
    float* out = (float*)d_out;

    const size_t NEED = 219152384;
    if (ws_size >= NEED) {
        char* ws = (char*)d_ws;
        float* attnP = (float*)ws;                    // KS*B*C*2C fp32 = 67,108,864
        f16*   KVhi  = (f16*)(ws + 67108864);         // 67,108,864
        f16*   KVT   = (f16*)(ws + 134217728);        // 67,108,864
        f16*   Whi   = (f16*)(ws + 201326592);        //    524,288
        f16*   Wlo   = (f16*)(ws + 201850880);        //    524,288
        f16*   attnT = (f16*)(ws + 202375168);        //  8,388,608
        f16*   A2hi  = (f16*)(ws + 210763776);        //  8,388,608

        dim3 blk(256);
        p_kv   <<<dim3(Ll / 64, KV2 / 64, Bq), blk, 0, stream>>>(sp, ms, KVhi, KVT);
        p_split<<<dim3(256),                   blk, 0, stream>>>(W, Whi, Wlo, Cc * Cc / 4);

        gemm_k1<<<dim3(KV2 / 128, Cc / 128, Bq * KS), blk, 0, stream>>>(x, KVhi, scale, attnP);

        k2_softmax_t<<<dim3(Cc / 16, Bq), blk, 0, stream>>>(attnP, attnT);

        gemm_nt<Cc, KV2, 1, true><<<dim3(KV2 / 128, Cc / 128, Bq), blk, 0, stream>>>(
            Whi, Wlo, (size_t)0, attnT, (size_t)KV2 * Cc,
            nullptr, nullptr, A2hi, (size_t)Cc * KV2);

        gemm_nt<KV2, Ll, 2, false><<<dim3(Ll / 128, Cc / 128, Bq), blk, 0, stream>>>(
            A2hi, nullptr, (size_t)Cc * KV2, KVT, (size_t)Ll * KV2,
            bias, out, nullptr, (size_t)Cc * Ll);
    } else {
        float* attn  = (float*)d_ws;
        float* attn2 = attn + (size_t)Bq * Cc * KV2;
        dim3 blk(256);
        k1_logits <<<dim3(KV2 / BN, Cc / BM, Bq), blk, 0, stream>>>(x, sp, ms, scale, attn);
        k2_softmax<<<dim3(Bq * Cc),               blk, 0, stream>>>(attn);
        k3_wattn  <<<dim3(KV2 / BN, Cc / BM, Bq), blk, 0, stream>>>(W, attn, attn2);
        k4_out    <<<dim3(Ll / BN, Cc / BM, Bq), blk, 0, stream>>>(attn2, sp, ms, bias, out);
    }
}

// Round 4
// 389.041 us; speedup vs baseline: 2.9864x; 1.0330x over previous
//
#include <hip/hip_runtime.h>

#define Bq   8
#define Cc   512
#define Ll   4096   // H*W
#define KV2  1024   // 2C
#define KS   4      // split-K factor for k1
#define KSL  (Ll / KS)

typedef _Float16 f16;
typedef __attribute__((ext_vector_type(4))) _Float16 f16x4;
typedef __attribute__((ext_vector_type(8))) _Float16 f16x8;
typedef __attribute__((ext_vector_type(4))) float    f32x4;

// ===========================================================================
// P: fp32 -> f16 (hi only), vectorized
// ===========================================================================
__global__ __launch_bounds__(256) void p_cvt(const float* __restrict__ in,
                                             f16* __restrict__ hi, int n4) {
    int i = blockIdx.x * 256 + threadIdx.x;
    if (i >= n4) return;
    float4 v = ((const float4*)in)[i];
    f16x4 hv; hv[0] = (f16)v.x; hv[1] = (f16)v.y; hv[2] = (f16)v.z; hv[3] = (f16)v.w;
    ((f16x4*)hi)[i] = hv;
}

// --- W fp32 -> hi/lo fp16 (small) -----------------------------------------
__global__ __launch_bounds__(256) void p_split(const float* __restrict__ in,
                                               f16* __restrict__ hi,
                                               f16* __restrict__ lo, int n4) {
    int i = blockIdx.x * 256 + threadIdx.x;
    if (i >= n4) return;
    float4 v = ((const float4*)in)[i];
    f16 h0 = (f16)v.x, h1 = (f16)v.y, h2 = (f16)v.z, h3 = (f16)v.w;
    f16x4 hv; hv[0] = h0; hv[1] = h1; hv[2] = h2; hv[3] = h3;
    f16x4 lv;
    lv[0] = (f16)(v.x - (float)h0); lv[1] = (f16)(v.y - (float)h1);
    lv[2] = (f16)(v.z - (float)h2); lv[3] = (f16)(v.w - (float)h3);
    ((f16x4*)hi)[i] = hv;
    ((f16x4*)lo)[i] = lv;
}

// ===========================================================================
// P: KV = concat(sp,ms) -> KVhi [b][2C][L] f16 + KVT [b][L][2C] f16.
// ===========================================================================
__global__ __launch_bounds__(256) void p_kv(const float* __restrict__ sp,
                                            const float* __restrict__ ms,
                                            f16* __restrict__ kvhi,
                                            f16* __restrict__ kvt) {
    __shared__ float tile[64][65];
    const int b = blockIdx.z, c0 = blockIdx.y * 64, l0 = blockIdx.x * 64;
    const int t = threadIdx.x;
    const int r = t >> 2, q = t & 3;
    const float* src = (c0 + r < Cc)
        ? sp + ((size_t)b * Cc + c0 + r) * Ll
        : ms + ((size_t)b * Cc + (c0 + r - Cc)) * Ll;
    #pragma unroll
    for (int i = 0; i < 4; ++i) {
        int col = q * 16 + i * 4;
        float4 v = *(const float4*)(src + l0 + col);
        f16x4 hv; hv[0] = (f16)v.x; hv[1] = (f16)v.y; hv[2] = (f16)v.z; hv[3] = (f16)v.w;
        *(f16x4*)&kvhi[((size_t)b * KV2 + c0 + r) * Ll + l0 + col] = hv;
        tile[r][col] = v.x; tile[r][col + 1] = v.y;
        tile[r][col + 2] = v.z; tile[r][col + 3] = v.w;
    }
    __syncthreads();
    const int ln = t >> 3, q8 = t & 7;
    #pragma unroll
    for (int p = 0; p < 2; ++p) {
        const int l = ln + 32 * p;
        f16x8 o;
        #pragma unroll
        for (int j = 0; j < 8; ++j) o[j] = (f16)tile[q8 * 8 + j][l];
        *(f16x8*)&kvt[((size_t)b * Ll + l0 + l) * KV2 + c0 + q8 * 8] = o;
    }
}

// ===========================================================================
// K1: split-K NT gemm, f16 A (pre-converted) x f16 B, f16 partial out.
// attnP[s][b][m][n] = alpha * sum_{k in slice s} Xhi[b][m][k] * KVhi[b][n][k]
// grid (KV2/128, Cc/128, Bq*KS)
// ===========================================================================
__global__ __launch_bounds__(256, 2) void gemm_k1(const f16* __restrict__ Xhi,
                                                  const f16* __restrict__ kvhi,
                                                  const float* __restrict__ scale_ptr,
                                                  f16* __restrict__ attnP) {
    __shared__ __align__(16) f16 sAh[128][40];
    __shared__ __align__(16) f16 sBn[128][40];

    const int z = blockIdx.z, b = z >> 2, s = z & 3;
    const int m0 = blockIdx.y * 128, n0 = blockIdx.x * 128;
    const int t = threadIdx.x;
    const int row = t >> 1, h = t & 1;
    const int w = t >> 6, lane = t & 63, quad = lane >> 4, lr = lane & 15;
    const int wm = (w & 1) * 64, wn = (w >> 1) * 64;

    const f16* gA = Xhi  + ((size_t)b * Cc  + m0 + row) * Ll + s * KSL;
    const f16* gB = kvhi + ((size_t)b * KV2 + n0 + row) * Ll + s * KSL;

    f32x4 acc[4][4];
    #pragma unroll
    for (int i = 0; i < 4; ++i)
        #pragma unroll
        for (int j = 0; j < 4; ++j) {
            acc[i][j][0] = 0.f; acc[i][j][1] = 0.f;
            acc[i][j][2] = 0.f; acc[i][j][3] = 0.f;
        }

    f16x8 ra0 = *(const f16x8*)(gA + 8 * h);
    f16x8 ra1 = *(const f16x8*)(gA + 8 * h + 16);
    f16x8 rb0 = *(const f16x8*)(gB + 8 * h);
    f16x8 rb1 = *(const f16x8*)(gB + 8 * h + 16);

    for (int k0 = 0; k0 < KSL; k0 += 32) {
        __syncthreads();
        *(f16x8*)&sAh[row][8 * h]      = ra0;
        *(f16x8*)&sAh[row][8 * h + 16] = ra1;
        *(f16x8*)&sBn[row][8 * h]      = rb0;
        *(f16x8*)&sBn[row][8 * h + 16] = rb1;
        __syncthreads();
        if (k0 + 32 < KSL) {
            ra0 = *(const f16x8*)(gA + k0 + 32 + 8 * h);
            ra1 = *(const f16x8*)(gA + k0 + 32 + 8 * h + 16);
            rb0 = *(const f16x8*)(gB + k0 + 32 + 8 * h);
            rb1 = *(const f16x8*)(gB + k0 + 32 + 8 * h + 16);
        }
        f16x8 af[4], bf[4];
        #pragma unroll
        for (int i = 0; i < 4; ++i)
            af[i] = *(const f16x8*)&sAh[wm + i * 16 + lr][8 * quad];
        #pragma unroll
        for (int j = 0; j < 4; ++j)
            bf[j] = *(const f16x8*)&sBn[wn + j * 16 + lr][8 * quad];
        #pragma unroll
        for (int i = 0; i < 4; ++i)
            #pragma unroll
            for (int j = 0; j < 4; ++j)
                acc[i][j] = __builtin_amdgcn_mfma_f32_16x16x32_f16(af[i], bf[j], acc[i][j], 0, 0, 0);
    }

    const float alpha = scale_ptr[0] * 0.015625f;
    f16* Cs = attnP + (size_t)s * Bq * Cc * KV2 + (size_t)b * Cc * KV2;
    #pragma unroll
    for (int i = 0; i < 4; ++i)
        #pragma unroll
        for (int j = 0; j < 4; ++j) {
            const int n = n0 + wn + j * 16 + lr;
            #pragma unroll
            for (int r = 0; r < 4; ++r) {
                const int m = m0 + wm + i * 16 + quad * 4 + r;
                Cs[(size_t)m * KV2 + n] = (f16)(alpha * acc[i][j][r]);
            }
        }
}

// ===========================================================================
// K2: sum KS f16 partials, softmax over last dim (1024), write attnT f16
// ===========================================================================
__global__ __launch_bounds__(256) void k2_softmax_t(const f16* __restrict__ attnP,
                                                    f16* __restrict__ attnT) {
    __shared__ float rmax[16], rinv[16];
    __shared__ __align__(16) f16 tile[16][68];
    const int b = blockIdx.y, c0 = blockIdx.x * 16;
    const int t = threadIdx.x, w = t >> 6, lane = t & 63;
    const size_t sS = (size_t)Bq * Cc * KV2;

    for (int rr = 0; rr < 4; ++rr) {
        const int r = w * 4 + rr;
        const f16* base = attnP + ((size_t)b * Cc + c0 + r) * KV2;
        float v[16];
        #pragma unroll
        for (int i = 0; i < 2; ++i) {
            f16x8 u = *(const f16x8*)(base + (lane + 64 * i) * 8);
            #pragma unroll
            for (int j = 0; j < 8; ++j) v[i * 8 + j] = (float)u[j];
        }
        #pragma unroll
        for (int s = 1; s < KS; ++s) {
            const f16* bs = base + (size_t)s * sS;
            #pragma unroll
            for (int i = 0; i < 2; ++i) {
                f16x8 u = *(const f16x8*)(bs + (lane + 64 * i) * 8);
                #pragma unroll
                for (int j = 0; j < 8; ++j) v[i * 8 + j] += (float)u[j];
            }
        }
        float m = -3.4e38f;
        #pragma unroll
        for (int i = 0; i < 16; ++i) m = fmaxf(m, v[i]);
        #pragma unroll
        for (int off = 32; off; off >>= 1) m = fmaxf(m, __shfl_xor(m, off));
        float s = 0.f;
        #pragma unroll
        for (int i = 0; i < 16; ++i) s += __expf(v[i] - m);
        #pragma unroll
        for (int off = 32; off; off >>= 1) s += __shfl_xor(s, off);
        if (lane == 0) { rmax[r] = m; rinv[r] = 1.0f / s; }
    }
    __syncthreads();

    const int r2 = t >> 4, cn = (t & 15) * 4;
    const int n4 = t >> 2, q = t & 3;
    for (int nt = 0; nt < 16; ++nt) {
        const f16* base = attnP + ((size_t)b * Cc + c0 + r2) * KV2 + nt * 64 + cn;
        float vx[4];
        {
            f16x4 u = *(const f16x4*)base;
            #pragma unroll
            for (int j = 0; j < 4; ++j) vx[j] = (float)u[j];
        }
        #pragma unroll
        for (int s = 1; s < KS; ++s) {
            f16x4 u = *(const f16x4*)(base + (size_t)s * sS);
            #pragma unroll
            for (int j = 0; j < 4; ++j) vx[j] += (float)u[j];
        }
        const float m = rmax[r2], iv = rinv[r2];
        f16x4 hv;
        hv[0] = (f16)(__expf(vx[0] - m) * iv); hv[1] = (f16)(__expf(vx[1] - m) * iv);
        hv[2] = (f16)(__expf(vx[2] - m) * iv); hv[3] = (f16)(__expf(vx[3] - m) * iv);
        *(f16x4*)&tile[r2][cn] = hv;
        __syncthreads();
        f16x4 o;
        o[0] = tile[q * 4 + 0][n4]; o[1] = tile[q * 4 + 1][n4];
        o[2] = tile[q * 4 + 2][n4]; o[3] = tile[q * 4 + 3][n4];
        *(f16x4*)&attnT[((size_t)b * KV2 + nt * 64 + n4) * Cc + c0 + q * 4] = o;
        __syncthreads();
    }
}

// ===========================================================================
// Generic NT GEMM (f16 inputs). LO: A has a lo-term. EPI 1: f16 out (k3).
// EPI 2: fp32 out + bias[m] (k4).
// ===========================================================================
template<int KD, int NC, int EPI, bool LO>
__global__ __launch_bounds__(256, 2) void gemm_nt(
    const f16* __restrict__ Ah, const f16* __restrict__ Al, size_t sA,
    const f16* __restrict__ Bh, size_t sB,
    const float* __restrict__ bias,
    float* __restrict__ Cf, f16* __restrict__ Chi, size_t sC) {
    __shared__ __align__(16) f16 sAh[128][40];
    __shared__ __align__(16) f16 sAl[LO ? 128 : 1][40];
    __shared__ __align__(16) f16 sBn[128][40];

    const int b = blockIdx.z, m0 = blockIdx.y * 128, n0 = blockIdx.x * 128;
    const int t = threadIdx.x;
    const int row = t >> 1, h = t & 1;
    const int w = t >> 6, lane = t & 63, quad = lane >> 4, lr = lane & 15;
    const int wm = (w & 1) * 64, wn = (w >> 1) * 64;

    const f16* gA  = Ah + b * sA + (size_t)(m0 + row) * KD;
    const f16* gAl = LO ? (Al + b * sA + (size_t)(m0 + row) * KD) : nullptr;
    const f16* gB  = Bh + b * sB + (size_t)(n0 + row) * KD;

    f32x4 acc[4][4];
    #pragma unroll
    for (int i = 0; i < 4; ++i)
        #pragma unroll
        for (int j = 0; j < 4; ++j) {
            acc[i][j][0] = 0.f; acc[i][j][1] = 0.f;
            acc[i][j][2] = 0.f; acc[i][j][3] = 0.f;
        }

    f16x8 ra0 = *(const f16x8*)(gA + 8 * h);
    f16x8 ra1 = *(const f16x8*)(gA + 8 * h + 16);
    f16x8 rl0, rl1;
    if constexpr (LO) {
        rl0 = *(const f16x8*)(gAl + 8 * h);
        rl1 = *(const f16x8*)(gAl + 8 * h + 16);
    }
    f16x8 rb0 = *(const f16x8*)(gB + 8 * h);
    f16x8 rb1 = *(const f16x8*)(gB + 8 * h + 16);

    for (int k0 = 0; k0 < KD; k0 += 32) {
        __syncthreads();
        *(f16x8*)&sAh[row][8 * h]      = ra0;
        *(f16x8*)&sAh[row][8 * h + 16] = ra1;
        if constexpr (LO) {
            *(f16x8*)&sAl[row][8 * h]      = rl0;
            *(f16x8*)&sAl[row][8 * h + 16] = rl1;
        }
        *(f16x8*)&sBn[row][8 * h]      = rb0;
        *(f16x8*)&sBn[row][8 * h + 16] = rb1;
        __syncthreads();
        if (k0 + 32 < KD) {
            ra0 = *(const f16x8*)(gA + k0 + 32 + 8 * h);
            ra1 = *(const f16x8*)(gA + k0 + 32 + 8 * h + 16);
            if constexpr (LO) {
                rl0 = *(const f16x8*)(gAl + k0 + 32 + 8 * h);
                rl1 = *(const f16x8*)(gAl + k0 + 32 + 8 * h + 16);
            }
            rb0 = *(const f16x8*)(gB + k0 + 32 + 8 * h);
            rb1 = *(const f16x8*)(gB + k0 + 32 + 8 * h + 16);
        }
        f16x8 af[4], alf[4], bf[4];
        #pragma unroll
        for (int i = 0; i < 4; ++i) {
            af[i] = *(const f16x8*)&sAh[wm + i * 16 + lr][8 * quad];
            if constexpr (LO) alf[i] = *(const f16x8*)&sAl[wm + i * 16 + lr][8 * quad];
        }
        #pragma unroll
        for (int j = 0; j < 4; ++j)
            bf[j] = *(const f16x8*)&sBn[wn + j * 16 + lr][8 * quad];
        #pragma unroll
        for (int i = 0; i < 4; ++i)
            #pragma unroll
            for (int j = 0; j < 4; ++j) {
                acc[i][j] = __builtin_amdgcn_mfma_f32_16x16x32_f16(af[i], bf[j], acc[i][j], 0, 0, 0);
                if constexpr (LO)
                    acc[i][j] = __builtin_amdgcn_mfma_f32_16x16x32_f16(alf[i], bf[j], acc[i][j], 0, 0, 0);
            }
    }

    #pragma unroll
    for (int i = 0; i < 4; ++i)
        #pragma unroll
        for (int j = 0; j < 4; ++j) {
            const int n = n0 + wn + j * 16 + lr;
            #pragma unroll
            for (int r = 0; r < 4; ++r) {
                const int m = m0 + wm + i * 16 + quad * 4 + r;
                const size_t idx = b * sC + (size_t)m * NC + n;
                const float v = acc[i][j][r];
                if constexpr (EPI == 1) Chi[idx] = (f16)v;
                else                    Cf[idx] = v + bias[m];
            }
        }
}

// ===========================================================================
// FALLBACK PATH (fp32, needs only 33.6 MB)
// ===========================================================================
#define BM 64
#define BN 64
#define BK 32
#define PAD 4

__device__ __forceinline__ const float* kv_row(const float* __restrict__ sp,
                                               const float* __restrict__ ms,
                                               int b, int k) {
    return (k < Cc) ? (sp + ((size_t)b * Cc + k) * Ll)
                    : (ms + ((size_t)b * Cc + (k - Cc)) * Ll);
}

__global__ __launch_bounds__(256) void k1_logits(const float* __restrict__ x,
                                                 const float* __restrict__ sp,
                                                 const float* __restrict__ ms,
                                                 const float* __restrict__ scale,
                                                 float* __restrict__ attn) {
    __shared__ __align__(16) float As[BK][BM + PAD];
    __shared__ __align__(16) float Bs[BK][BN + PAD];
    const int b = blockIdx.z, m0 = blockIdx.y * BM, n0 = blockIdx.x * BN;
    const int t = threadIdx.x, tx = t & 15, ty = t >> 4, q = t & 7, r = t >> 3;
    const float alpha = scale[0] * (1.0f / 64.0f);
    const float* Abase = x + (size_t)b * Cc * Ll;
    float acc[4][4] = {};
    for (int k0 = 0; k0 < Ll; k0 += BK) {
        #pragma unroll
        for (int hh = 0; hh < 2; ++hh) {
            const int rw = r + 32 * hh;
            float4 v = *(const float4*)(Abase + (size_t)(m0 + rw) * Ll + k0 + 4 * q);
            As[4*q+0][rw] = v.x; As[4*q+1][rw] = v.y; As[4*q+2][rw] = v.z; As[4*q+3][rw] = v.w;
        }
        #pragma unroll
        for (int hh = 0; hh < 2; ++hh) {
            const int rw = r + 32 * hh;
            const float* Brow = kv_row(sp, ms, b, n0 + rw);
            float4 v = *(const float4*)(Brow + k0 + 4 * q);
            Bs[4*q+0][rw] = v.x; Bs[4*q+1][rw] = v.y; Bs[4*q+2][rw] = v.z; Bs[4*q+3][rw] = v.w;
        }
        __syncthreads();
        #pragma unroll
        for (int k = 0; k < BK; ++k) {
            float a[4], bb[4];
            *(float4*)a  = *(const float4*)&As[k][4 * ty];
            *(float4*)bb = *(const float4*)&Bs[k][4 * tx];
            #pragma unroll
            for (int i = 0; i < 4; ++i)
                #pragma unroll
                for (int j = 0; j < 4; ++j) acc[i][j] += a[i] * bb[j];
        }
        __syncthreads();
    }
    #pragma unroll
    for (int i = 0; i < 4; ++i) {
        const int m = m0 + 4 * ty + i;
        float4 o;
        o.x = alpha * acc[i][0]; o.y = alpha * acc[i][1];
        o.z = alpha * acc[i][2]; o.w = alpha * acc[i][3];
        *(float4*)(attn + ((size_t)b * Cc + m) * KV2 + n0 + 4 * tx) = o;
    }
}

__global__ __launch_bounds__(256) void k2_softmax(float* __restrict__ attn) {
    float* p = attn + (size_t)blockIdx.x * KV2;
    const int t = threadIdx.x, lane = t & 63, wv = t >> 6;
    float4 v = ((const float4*)p)[t];
    float m = fmaxf(fmaxf(v.x, v.y), fmaxf(v.z, v.w));
    #pragma unroll
    for (int off = 32; off; off >>= 1) m = fmaxf(m, __shfl_down(m, off));
    __shared__ float redm[4];
    if (lane == 0) redm[wv] = m;
    __syncthreads();
    m = fmaxf(fmaxf(redm[0], redm[1]), fmaxf(redm[2], redm[3]));
    v.x = __expf(v.x - m); v.y = __expf(v.y - m);
    v.z = __expf(v.z - m); v.w = __expf(v.w - m);
    float s = v.x + v.y + v.z + v.w;
    #pragma unroll
    for (int off = 32; off; off >>= 1) s += __shfl_down(s, off);
    __shared__ float reds[4];
    if (lane == 0) reds[wv] = s;
    __syncthreads();
    s = reds[0] + reds[1] + reds[2] + reds[3];
    const float inv = 1.0f / s;
    v.x *= inv; v.y *= inv; v.z *= inv; v.w *= inv;
    ((float4*)p)[t] = v;
}

__global__ __launch_bounds__(256) void k3_wattn(const float* __restrict__ W,
                                                const float* __restrict__ attn,
                                                float* __restrict__ attn2) {
    __shared__ __align__(16) float As[BK][BM + PAD];
    __shared__ __align__(16) float Bs[BK][BN];
    const int b = blockIdx.z, m0 = blockIdx.y * BM, n0 = blockIdx.x * BN;
    const int t = threadIdx.x, tx = t & 15, ty = t >> 4;
    const int q = t & 7, r = t >> 3, c4 = t & 15, kr = t >> 4;
    const float* Bbase = attn + (size_t)b * Cc * KV2;
    float acc[4][4] = {};
    for (int k0 = 0; k0 < Cc; k0 += BK) {
        #pragma unroll
        for (int hh = 0; hh < 2; ++hh) {
            const int rw = r + 32 * hh;
            float4 v = *(const float4*)(W + (size_t)(m0 + rw) * Cc + k0 + 4 * q);
            As[4*q+0][rw] = v.x; As[4*q+1][rw] = v.y; As[4*q+2][rw] = v.z; As[4*q+3][rw] = v.w;
        }
        #pragma unroll
        for (int hh = 0; hh < 2; ++hh) {
            const int k = kr + 16 * hh;
            float4 v = *(const float4*)(Bbase + (size_t)(k0 + k) * KV2 + n0 + 4 * c4);
            *(float4*)&Bs[k][4 * c4] = v;
        }
        __syncthreads();
        #pragma unroll
        for (int k = 0; k < BK; ++k) {
            float a[4], bb[4];
            *(float4*)a  = *(const float4*)&As[k][4 * ty];
            *(float4*)bb = *(const float4*)&Bs[k][4 * tx];
            #pragma unroll
            for (int i = 0; i < 4; ++i)
                #pragma unroll
                for (int j = 0; j < 4; ++j) acc[i][j] += a[i] * bb[j];
        }
        __syncthreads();
    }
    #pragma unroll
    for (int i = 0; i < 4; ++i) {
        const int m = m0 + 4 * ty + i;
        float4 o;
        o.x = acc[i][0]; o.y = acc[i][1]; o.z = acc[i][2]; o.w = acc[i][3];
        *(float4*)(attn2 + ((size_t)b * Cc + m) * KV2 + n0 + 4 * tx) = o;
    }
}

__global__ __launch_bounds__(256) void k4_out(const float* __restrict__ attn2,
                                              const float* __restrict__ sp,
                                              const float* __restrict__ ms,
                                              const float* __restrict__ bias,
                                              float* __restrict__ out) {
    __shared__ __align__(16) float As[BK][BM + PAD];
    __shared__ __align__(16) float Bs[BK][BN];
    const int b = blockIdx.z, m0 = blockIdx.y * BM, n0 = blockIdx.x * BN;
    const int t = threadIdx.x, tx = t & 15, ty = t >> 4;
    const int q = t & 7, r = t >> 3, c4 = t & 15, kr = t >> 4;
    const float* Abase = attn2 + (size_t)b * Cc * KV2;
    float acc[4][4] = {};
    for (int k0 = 0; k0 < KV2; k0 += BK) {
        #pragma unroll
        for (int hh = 0; hh < 2; ++hh) {
            const int rw = r + 32 * hh;
            float4 v = *(const float4*)(Abase + (size_t)(m0 + rw) * KV2 + k0 + 4 * q);
            As[4*q+0][rw] = v.x; As[4*q+1][rw] = v.y; As[4*q+2][rw] = v.z; As[4*q+3][rw] = v.w;
        }
        #pragma unroll
        for (int hh = 0; hh < 2; ++hh) {
            const int k = kr + 16 * hh;
            const float* Brow = kv_row(sp, ms, b, k0 + k);
            float4 v = *(const float4*)(Brow + n0 + 4 * c4);
            *(float4*)&Bs[k][4 * c4] = v;
        }
        __syncthreads();
        #pragma unroll
        for (int k = 0; k < BK; ++k) {
            float a[4], bb[4];
            *(float4*)a  = *(const float4*)&As[k][4 * ty];
            *(float4*)bb = *(const float4*)&Bs[k][4 * tx];
            #pragma unroll
            for (int i = 0; i < 4; ++i)
                #pragma unroll
                for (int j = 0; j < 4; ++j) acc[i][j] += a[i] * bb[j];
        }
        __syncthreads();
    }
    #pragma unroll
    for (int i = 0; i < 4; ++i) {
        const int m = m0 + 4 * ty + i;
        const float bm = bias[m];
        float4 o;
        o.x = acc[i][0] + bm; o.y = acc[i][1] + bm;
        o.z = acc[i][2] + bm; o.w = acc[i][3] + bm;
        *(float4*)(out + ((size_t)b * Cc + m) * Ll + n0 + 4 * tx) = o;
    }
}

// ===========================================================================
extern "C" void kernel_launch(void* const* d_in, const int* in_sizes, int n_in,
                              void* d_out, int out_size, void* d_ws, size_t ws_size,
                              hipStream_t stream) {
    const float* x     = (const float*)d_in[0];
    const float* sp    = (const float*)d_in[1];
    const float* ms    = (const float*)d_in[2];
    const float* scale = (const float*)d_in[3];
    const float* W     = (const float*)d_in[4];
    const float* bias  = (const float*)d_in[5];
    float* out = (float*)d_out;

    const size_t NEED = 219152384;
    if (ws_size >= NEED) {
        char* ws = (char*)d_ws;
        f16* attnP = (f16*)ws;                      // KS*B*C*2C f16 = 33,554,432
        f16* Xhi   = (f16*)(ws + 33554432);         // 33,554,432
        f16* KVhi  = (f16*)(ws + 67108864);         // 67,108,864
        f16* KVT   = (f16*)(ws + 134217728);        // 67,108,864
        f16* Whi   = (f16*)(ws + 201326592);        //    524,288
        f16* Wlo   = (f16*)(ws + 201850880);        //    524,288
        f16* attnT = (f16*)(ws + 202375168);        //  8,388,608
        f16* A2hi  = (f16*)(ws + 210763776);        //  8,388,608

        dim3 blk(256);
        p_cvt  <<<dim3(16384),                 blk, 0, stream>>>(x, Xhi, Bq * Cc * Ll / 4);
        p_kv   <<<dim3(Ll / 64, KV2 / 64, Bq), blk, 0, stream>>>(sp, ms, KVhi, KVT);
        p_split<<<dim3(256),                   blk, 0, stream>>>(W, Whi, Wlo, Cc * Cc / 4);

        gemm_k1<<<dim3(KV2 / 128, Cc / 128, Bq * KS), blk, 0, stream>>>(Xhi, KVhi, scale, attnP);

        k2_softmax_t<<<dim3(Cc / 16, Bq), blk, 0, stream>>>(attnP, attnT);

        gemm_nt<Cc, KV2, 1, true><<<dim3(KV2 / 128, Cc / 128, Bq), blk, 0, stream>>>(
            Whi, Wlo, (size_t)0, attnT, (size_t)KV2 * Cc,
            nullptr, nullptr, A2hi, (size_t)Cc * KV2);

        gemm_nt<KV2, Ll, 2, false><<<dim3(Ll / 128, Cc / 128, Bq), blk, 0, stream>>>(
            A2hi, nullptr, (size_t)Cc * KV2, KVT, (size_t)Ll * KV2,
            bias, out, nullptr, (size_t)Cc * Ll);
    } else {
        float* attn  = (float*)d_ws;
        float* attn2 = attn + (size_t)Bq * Cc * KV2;
        dim3 blk(256);
        k1_logits <<<dim3(KV2 / BN, Cc / BM, Bq), blk, 0, stream>>>(x, sp, ms, scale, attn);
        k2_softmax<<<dim3(Bq * Cc),               blk, 0, stream>>>(attn);
        k3_wattn  <<<dim3(KV2 / BN, Cc / BM, Bq), blk, 0, stream>>>(W, attn, attn2);
        k4_out    <<<dim3(Ll / BN, Cc / BM, Bq), blk, 0, stream>>>(attn2, sp, ms, bias, out);
    }
}